// Round 15
// baseline (266.382 us; speedup 1.0000x reference)
//
#include <hip/hip_runtime.h>
#include <math.h>

#define MAXT 100000.0f
#define M_OUT 1024
#define BATCH 64
#define PITCH 1040      // 1025 real + pads covering depth-4 offset overrun (off4 idx <= 259)
#define NSEG 16
#define SEGLEN 64

#define WALL() __builtin_amdgcn_sched_barrier(0)

// ---------------------------------------------------------------------------
// Kernel 1 (R13, verified): stable rank via u32 keys, split-j.
// key = ((mantissa bits) >> 2) << 11 | index — ties fall to index order =
// adjacent-swap perturbation, compensated (validated R9-R14: absmax 16).
// Writes TRUE x to sx, byte row offsets to soff; rewrites pads [1025,1040)
// every launch (ws re-poisoned 0xAA).
// ---------------------------------------------------------------------------
__global__ __launch_bounds__(512) void rank_kernel(const float* __restrict__ X,
                                                   float* __restrict__ sx,
                                                   int* __restrict__ soff) {
    const int b   = blockIdx.y;
    const int tid = threadIdx.x;            // 0..511
    const int t   = tid & 255;              // key slot within block
    const int i   = blockIdx.x * 256 + t;   // key index 0..1279
    __shared__ __align__(16) unsigned keys[1032];
    __shared__ int part[256];

    const float myx = (i < 1024) ? X[b * 1024 + i] : 1.0f;

#pragma unroll
    for (int c = 0; c < 2; ++c) {
        const int ii = c * 512 + tid;
        const float v = X[b * 1024 + ii];
        keys[ii] = (((__float_as_uint(v) - 0x3F800000u) >> 2) << 11) | (unsigned)ii;
    }
    if (tid == 0) keys[1024] = 1024u;                       // bias: mantissa 0 | idx 1024
    else if (tid < 8) keys[1024 + tid] = 0xFFFFFFFFu;       // pads: > all real keys
    __syncthreads();

    const unsigned ki = keys[(i < 1032) ? i : 1031];        // guard OOB LDS read
    const int j0 = (tid < 256) ? 0 : 516;
    int r0 = 0, r1 = 0;
#pragma unroll 8
    for (int j = j0; j < j0 + 512; j += 8) {
        const uint4 a = *(const uint4*)&keys[j];
        const uint4 c = *(const uint4*)&keys[j + 4];
        r0 += (int)(a.x < ki) + (int)(a.y < ki) + (int)(a.z < ki) + (int)(a.w < ki);
        r1 += (int)(c.x < ki) + (int)(c.y < ki) + (int)(c.z < ki) + (int)(c.w < ki);
    }
    {   // 516 = 512 + last quad of the half-range
        const uint4 a = *(const uint4*)&keys[j0 + 512];
        r0 += (int)(a.x < ki) + (int)(a.y < ki) + (int)(a.z < ki) + (int)(a.w < ki);
    }
    if (tid >= 256) part[t] = r0 + r1;
    __syncthreads();

    if (tid < 256) {
        if (i <= 1024) {
            const int rank = r0 + r1 + part[t];
            sx[b * PITCH + rank]   = myx;
            soff[b * PITCH + rank] = i * 4096;              // byte offset into W
        } else if (i < PITCH) {
            sx[b * PITCH + i] = MAXT; soff[b * PITCH + i] = 0;  // sentinels
        }
    }
}

// ---------------------------------------------------------------------------
// Kernel 2: decoupled two-pass K-scan (16 waves = 16 segments, 4 cols/lane),
// DEPTH-4 circular-buffer pipeline: fully-unrolled 16-iter loop; iter it
// computes buf[it&3] (rows k0+4*it) then reloads that buffer with rows
// k0+4*(it+4). No buffer rotation copies (R3/R4 collapse vector), 12 float4
// loads in flight, load->use distance ~3 compute sections (~450 cyc).
// Budget ~100 VGPR <= 128 cap (1024-thr block = 4 waves/SIMD) — R13's 8-row
// dual-buffer needed ~150 and spilled (WRITE_SIZE 80 MB).
// Step algebra unchanged since R11 (absmax 16): first-valid lock via bd sign,
// cross-multiplied gates, one IEEE div at the end.
// ---------------------------------------------------------------------------
__global__ __launch_bounds__(1024, 4) void snn_scan(const float* __restrict__ W,
                                                    const float* __restrict__ sx,
                                                    const int* __restrict__ soff,
                                                    float* __restrict__ out) {
    const int b    = blockIdx.y;
    const int tid  = threadIdx.x;
    const int w    = tid >> 6;        // wave = K-segment id, 0..15
    const int lane = tid & 63;

    __shared__ __align__(16) float xs_s[PITCH];
    __shared__ __align__(16) int   off_s[PITCH];
    __shared__ __align__(16) float segw [NSEG][256];
    __shared__ __align__(16) float segwt[NSEG][256];
    __shared__ __align__(16) float best [NSEG][256];

    xs_s[tid]  = sx[b * PITCH + tid];
    off_s[tid] = soff[b * PITCH + tid];
    if (tid < PITCH - 1024) {
        xs_s[1024 + tid]  = sx[b * PITCH + 1024 + tid];
        off_s[1024 + tid] = soff[b * PITCH + 1024 + tid];
    }
    __syncthreads();

    const char* Wq = (const char*)W + (size_t)(blockIdx.x * 256 + lane * 4) * 4;
    const int4* off4 = (const int4*)off_s;
    const int k0 = w * SEGLEN;
    const int base = k0 >> 2;         // first int4 slot of this segment

#define LOADB(dst, o)                                                          \
    do {                                                                       \
        dst[0] = *(const float4*)(Wq + (o).x);                                 \
        dst[1] = *(const float4*)(Wq + (o).y);                                 \
        dst[2] = *(const float4*)(Wq + (o).z);                                 \
        dst[3] = *(const float4*)(Wq + (o).w);                                 \
    } while (0)

    float cw0 = 0, cw1 = 0, cw2 = 0, cw3 = 0;
    float ct0 = 0, ct1 = 0, ct2 = 0, ct3 = 0;

#define ACC(wv, xx)                                                            \
    do {                                                                       \
        cw0 = __fadd_rn(cw0, (wv).x); ct0 = __builtin_fmaf((wv).x, (xx), ct0); \
        cw1 = __fadd_rn(cw1, (wv).y); ct1 = __builtin_fmaf((wv).y, (xx), ct1); \
        cw2 = __fadd_rn(cw2, (wv).z); ct2 = __builtin_fmaf((wv).z, (xx), ct2); \
        cw3 = __fadd_rn(cw3, (wv).w); ct3 = __builtin_fmaf((wv).w, (xx), ct3); \
    } while (0)

    // ---- pass 1: segment sums, depth-4 circular pipeline ----
    {
        float4 buf[4][4];
#pragma unroll
        for (int p = 0; p < 4; ++p) { const int4 o = off4[base + p]; LOADB(buf[p], o); }
        WALL();
#pragma unroll
        for (int it = 0; it < 16; ++it) {
            const int k = k0 + it * 4;
            ACC(buf[it & 3][0], xs_s[k]);
            ACC(buf[it & 3][1], xs_s[k + 1]);
            ACC(buf[it & 3][2], xs_s[k + 2]);
            ACC(buf[it & 3][3], xs_s[k + 3]);
            WALL();
            const int4 o = off4[base + it + 4];    // pads safe (<= off4[259])
            LOADB(buf[it & 3], o);
            WALL();
        }
    }
    *(float4*)&segw[w][lane * 4]  = make_float4(cw0, cw1, cw2, cw3);
    *(float4*)&segwt[w][lane * 4] = make_float4(ct0, ct1, ct2, ct3);
    __syncthreads();

    // ---- exclusive prefix over segments (ascending s) ----
    cw0 = cw1 = cw2 = cw3 = ct0 = ct1 = ct2 = ct3 = 0.0f;
    for (int s = 0; s < w; ++s) {
        const float4 a = *(const float4*)&segw[s][lane * 4];
        const float4 t = *(const float4*)&segwt[s][lane * 4];
        cw0 = __fadd_rn(cw0, a.x); cw1 = __fadd_rn(cw1, a.y);
        cw2 = __fadd_rn(cw2, a.z); cw3 = __fadd_rn(cw3, a.w);
        ct0 = __fadd_rn(ct0, t.x); ct1 = __fadd_rn(ct1, t.y);
        ct2 = __fadd_rn(ct2, t.z); ct3 = __fadd_rn(ct3, t.w);
    }

    // ---- pass 2: gated scan, first-valid lock, depth-4 circular pipeline ----
    float bn0 = 0, bn1 = 0, bn2 = 0, bn3 = 0;
    float bd0 = -1.0f, bd1 = -1.0f, bd2 = -1.0f, bd3 = -1.0f;

#define GATE(cwv, ctv, bnv, bdv, wvv, xx, xxn)                                 \
    do {                                                                       \
        cwv = __fadd_rn(cwv, (wvv));                                           \
        ctv = __builtin_fmaf((wvv), (xx), ctv);                                \
        const float dn = __fadd_rn(cwv, -1.0f);                                \
        const bool v = (ctv >= __fmul_rn((xx), dn))                            \
                     & (ctv <= __fmul_rn((xxn), dn));                          \
        const bool u = v & (bdv < 0.0f);                                       \
        bnv = u ? ctv : bnv;                                                   \
        bdv = u ? dn  : bdv;                                                   \
    } while (0)

#define GATE4(wv, xx, xxn)                                                     \
    do {                                                                       \
        GATE(cw0, ct0, bn0, bd0, (wv).x, (xx), (xxn));                         \
        GATE(cw1, ct1, bn1, bd1, (wv).y, (xx), (xxn));                         \
        GATE(cw2, ct2, bn2, bd2, (wv).z, (xx), (xxn));                         \
        GATE(cw3, ct3, bn3, bd3, (wv).w, (xx), (xxn));                         \
    } while (0)

    {
        float4 buf[4][4];
#pragma unroll
        for (int p = 0; p < 4; ++p) { const int4 o = off4[base + p]; LOADB(buf[p], o); }
        WALL();
#pragma unroll
        for (int it = 0; it < 16; ++it) {
            const int k = k0 + it * 4;
            const float xa = xs_s[k],     xb = xs_s[k + 1];
            const float xc = xs_s[k + 2], xd = xs_s[k + 3], xe = xs_s[k + 4];
            GATE4(buf[it & 3][0], xa, xb);
            GATE4(buf[it & 3][1], xb, xc);
            GATE4(buf[it & 3][2], xc, xd);
            GATE4(buf[it & 3][3], xd, xe);
            WALL();
            const int4 o = off4[base + it + 4];
            LOADB(buf[it & 3], o);
            WALL();
        }
        if (w == NSEG - 1) {
            // epilogue row 1024: buf[0] was reloaded at it=12 from off4[base+16],
            // whose .x slot is off_s[1024]
            GATE4(buf[0][0], xs_s[1024], xs_s[1025]);       // xs_s[1025] = MAXT pad
        }
    }

    const float c0 = (bd0 > 0.0f) ? bn0 / bd0 : MAXT;       // exact IEEE div
    const float c1 = (bd1 > 0.0f) ? bn1 / bd1 : MAXT;
    const float c2 = (bd2 > 0.0f) ? bn2 / bd2 : MAXT;
    const float c3 = (bd3 > 0.0f) ? bn3 / bd3 : MAXT;
    *(float4*)&best[w][lane * 4] = make_float4(c0, c1, c2, c3);
    __syncthreads();

    // ---- cross-segment min + store ----
    if (tid < 256) {
        float r = best[0][tid];
#pragma unroll
        for (int s = 1; s < NSEG; ++s) r = fminf(r, best[s][tid]);
        out[b * M_OUT + blockIdx.x * 256 + tid] = r;
    }
}

extern "C" void kernel_launch(void* const* d_in, const int* in_sizes, int n_in,
                              void* d_out, int out_size, void* d_ws, size_t ws_size,
                              hipStream_t stream) {
    const float* X = (const float*)d_in[0];   // [64, 1024]
    const float* W = (const float*)d_in[1];   // [1025, 1024]
    float* out = (float*)d_out;               // [64, 1024]

    float* sx   = (float*)d_ws;                                        // [64, PITCH]
    int*   soff = (int*)((char*)d_ws + BATCH * PITCH * sizeof(float)); // [64, PITCH]

    dim3 g1(5, BATCH);
    rank_kernel<<<g1, 512, 0, stream>>>(X, sx, soff);

    dim3 g2(M_OUT / 256, BATCH);
    snn_scan<<<g2, 1024, 0, stream>>>(W, sx, soff, out);
}

// Round 16
// 253.152 us; speedup vs baseline: 1.0523x; 1.0523x over previous
//
#include <hip/hip_runtime.h>
#include <math.h>

#define MAXT 100000.0f
#define M_OUT 1024
#define BATCH 64
#define PITCH 1040      // 1025 real + pads covering depth-4 offset overrun (off4 idx <= 259)
#define NSEG 16
#define SEGLEN 64

#define WALL() __builtin_amdgcn_sched_barrier(0)

// ---------------------------------------------------------------------------
// Kernel 1 (R13, verified): stable rank via u32 keys, split-j.
// key = ((mantissa bits) >> 2) << 11 | index — ties fall to index order =
// adjacent-swap perturbation, compensated (validated R9-R15: absmax 16).
// Writes TRUE x to sx, byte row offsets to soff; rewrites pads [1025,1040)
// every launch (ws re-poisoned 0xAA).
// ---------------------------------------------------------------------------
__global__ __launch_bounds__(512) void rank_kernel(const float* __restrict__ X,
                                                   float* __restrict__ sx,
                                                   int* __restrict__ soff) {
    const int b   = blockIdx.y;
    const int tid = threadIdx.x;            // 0..511
    const int t   = tid & 255;              // key slot within block
    const int i   = blockIdx.x * 256 + t;   // key index 0..1279
    __shared__ __align__(16) unsigned keys[1032];
    __shared__ int part[256];

    const float myx = (i < 1024) ? X[b * 1024 + i] : 1.0f;

#pragma unroll
    for (int c = 0; c < 2; ++c) {
        const int ii = c * 512 + tid;
        const float v = X[b * 1024 + ii];
        keys[ii] = (((__float_as_uint(v) - 0x3F800000u) >> 2) << 11) | (unsigned)ii;
    }
    if (tid == 0) keys[1024] = 1024u;                       // bias: mantissa 0 | idx 1024
    else if (tid < 8) keys[1024 + tid] = 0xFFFFFFFFu;       // pads: > all real keys
    __syncthreads();

    const unsigned ki = keys[(i < 1032) ? i : 1031];        // guard OOB LDS read
    const int j0 = (tid < 256) ? 0 : 516;
    int r0 = 0, r1 = 0;
#pragma unroll 8
    for (int j = j0; j < j0 + 512; j += 8) {
        const uint4 a = *(const uint4*)&keys[j];
        const uint4 c = *(const uint4*)&keys[j + 4];
        r0 += (int)(a.x < ki) + (int)(a.y < ki) + (int)(a.z < ki) + (int)(a.w < ki);
        r1 += (int)(c.x < ki) + (int)(c.y < ki) + (int)(c.z < ki) + (int)(c.w < ki);
    }
    {   // 516 = 512 + last quad of the half-range
        const uint4 a = *(const uint4*)&keys[j0 + 512];
        r0 += (int)(a.x < ki) + (int)(a.y < ki) + (int)(a.z < ki) + (int)(a.w < ki);
    }
    if (tid >= 256) part[t] = r0 + r1;
    __syncthreads();

    if (tid < 256) {
        if (i <= 1024) {
            const int rank = r0 + r1 + part[t];
            sx[b * PITCH + rank]   = myx;
            soff[b * PITCH + rank] = i * 4096;              // byte offset into W
        } else if (i < PITCH) {
            sx[b * PITCH + i] = MAXT; soff[b * PITCH + i] = 0;  // sentinels
        }
    }
}

// ---------------------------------------------------------------------------
// Kernel 2: decoupled two-pass K-scan (16 waves = 16 segments, 4 cols/lane),
// depth-4 circular-buffer pipeline (R15) + amdgpu_waves_per_eu(4,4):
// R10/R13/R15 showed the allocator targets 8 waves/EU (64 VGPR) regardless
// of launch_bounds' 128-VGPR legality -> buf[4][4] spilled (R15: 408 MB
// scratch writes). min=max=4 waves/EU pins the budget at 128 VGPR; with
// 256 blocks on 256 CUs we run 4 waves/SIMD anyway, so zero occupancy cost.
// Iter it computes buf[it&3] (rows k0+4*it) then reloads it with rows
// k0+4*(it+4): no rotation copies, 12 float4 loads in flight, load->use
// distance ~3 compute sections. Step algebra unchanged since R11 (absmax 16).
// ---------------------------------------------------------------------------
__global__ __launch_bounds__(1024, 4)
__attribute__((amdgpu_waves_per_eu(4, 4)))
void snn_scan(const float* __restrict__ W,
              const float* __restrict__ sx,
              const int* __restrict__ soff,
              float* __restrict__ out) {
    const int b    = blockIdx.y;
    const int tid  = threadIdx.x;
    const int w    = tid >> 6;        // wave = K-segment id, 0..15
    const int lane = tid & 63;

    __shared__ __align__(16) float xs_s[PITCH];
    __shared__ __align__(16) int   off_s[PITCH];
    __shared__ __align__(16) float segw [NSEG][256];
    __shared__ __align__(16) float segwt[NSEG][256];
    __shared__ __align__(16) float best [NSEG][256];

    xs_s[tid]  = sx[b * PITCH + tid];
    off_s[tid] = soff[b * PITCH + tid];
    if (tid < PITCH - 1024) {
        xs_s[1024 + tid]  = sx[b * PITCH + 1024 + tid];
        off_s[1024 + tid] = soff[b * PITCH + 1024 + tid];
    }
    __syncthreads();

    const char* Wq = (const char*)W + (size_t)(blockIdx.x * 256 + lane * 4) * 4;
    const int4* off4 = (const int4*)off_s;
    const int k0 = w * SEGLEN;
    const int base = k0 >> 2;         // first int4 slot of this segment

#define LOADB(dst, o)                                                          \
    do {                                                                       \
        dst[0] = *(const float4*)(Wq + (o).x);                                 \
        dst[1] = *(const float4*)(Wq + (o).y);                                 \
        dst[2] = *(const float4*)(Wq + (o).z);                                 \
        dst[3] = *(const float4*)(Wq + (o).w);                                 \
    } while (0)

    float cw0 = 0, cw1 = 0, cw2 = 0, cw3 = 0;
    float ct0 = 0, ct1 = 0, ct2 = 0, ct3 = 0;

#define ACC(wv, xx)                                                            \
    do {                                                                       \
        cw0 = __fadd_rn(cw0, (wv).x); ct0 = __builtin_fmaf((wv).x, (xx), ct0); \
        cw1 = __fadd_rn(cw1, (wv).y); ct1 = __builtin_fmaf((wv).y, (xx), ct1); \
        cw2 = __fadd_rn(cw2, (wv).z); ct2 = __builtin_fmaf((wv).z, (xx), ct2); \
        cw3 = __fadd_rn(cw3, (wv).w); ct3 = __builtin_fmaf((wv).w, (xx), ct3); \
    } while (0)

    // ---- pass 1: segment sums, depth-4 circular pipeline ----
    {
        float4 buf[4][4];
#pragma unroll
        for (int p = 0; p < 4; ++p) { const int4 o = off4[base + p]; LOADB(buf[p], o); }
        WALL();
#pragma unroll
        for (int it = 0; it < 16; ++it) {
            const int k = k0 + it * 4;
            ACC(buf[it & 3][0], xs_s[k]);
            ACC(buf[it & 3][1], xs_s[k + 1]);
            ACC(buf[it & 3][2], xs_s[k + 2]);
            ACC(buf[it & 3][3], xs_s[k + 3]);
            WALL();
            const int4 o = off4[base + it + 4];    // pads safe (<= off4[259])
            LOADB(buf[it & 3], o);
            WALL();
        }
    }
    *(float4*)&segw[w][lane * 4]  = make_float4(cw0, cw1, cw2, cw3);
    *(float4*)&segwt[w][lane * 4] = make_float4(ct0, ct1, ct2, ct3);
    __syncthreads();

    // ---- exclusive prefix over segments (ascending s) ----
    cw0 = cw1 = cw2 = cw3 = ct0 = ct1 = ct2 = ct3 = 0.0f;
    for (int s = 0; s < w; ++s) {
        const float4 a = *(const float4*)&segw[s][lane * 4];
        const float4 t = *(const float4*)&segwt[s][lane * 4];
        cw0 = __fadd_rn(cw0, a.x); cw1 = __fadd_rn(cw1, a.y);
        cw2 = __fadd_rn(cw2, a.z); cw3 = __fadd_rn(cw3, a.w);
        ct0 = __fadd_rn(ct0, t.x); ct1 = __fadd_rn(ct1, t.y);
        ct2 = __fadd_rn(ct2, t.z); ct3 = __fadd_rn(ct3, t.w);
    }

    // ---- pass 2: gated scan, first-valid lock, depth-4 circular pipeline ----
    float bn0 = 0, bn1 = 0, bn2 = 0, bn3 = 0;
    float bd0 = -1.0f, bd1 = -1.0f, bd2 = -1.0f, bd3 = -1.0f;

#define GATE(cwv, ctv, bnv, bdv, wvv, xx, xxn)                                 \
    do {                                                                       \
        cwv = __fadd_rn(cwv, (wvv));                                           \
        ctv = __builtin_fmaf((wvv), (xx), ctv);                                \
        const float dn = __fadd_rn(cwv, -1.0f);                                \
        const bool v = (ctv >= __fmul_rn((xx), dn))                            \
                     & (ctv <= __fmul_rn((xxn), dn));                          \
        const bool u = v & (bdv < 0.0f);                                       \
        bnv = u ? ctv : bnv;                                                   \
        bdv = u ? dn  : bdv;                                                   \
    } while (0)

#define GATE4(wv, xx, xxn)                                                     \
    do {                                                                       \
        GATE(cw0, ct0, bn0, bd0, (wv).x, (xx), (xxn));                         \
        GATE(cw1, ct1, bn1, bd1, (wv).y, (xx), (xxn));                         \
        GATE(cw2, ct2, bn2, bd2, (wv).z, (xx), (xxn));                         \
        GATE(cw3, ct3, bn3, bd3, (wv).w, (xx), (xxn));                         \
    } while (0)

    {
        float4 buf[4][4];
#pragma unroll
        for (int p = 0; p < 4; ++p) { const int4 o = off4[base + p]; LOADB(buf[p], o); }
        WALL();
#pragma unroll
        for (int it = 0; it < 16; ++it) {
            const int k = k0 + it * 4;
            const float xa = xs_s[k],     xb = xs_s[k + 1];
            const float xc = xs_s[k + 2], xd = xs_s[k + 3], xe = xs_s[k + 4];
            GATE4(buf[it & 3][0], xa, xb);
            GATE4(buf[it & 3][1], xb, xc);
            GATE4(buf[it & 3][2], xc, xd);
            GATE4(buf[it & 3][3], xd, xe);
            WALL();
            const int4 o = off4[base + it + 4];
            LOADB(buf[it & 3], o);
            WALL();
        }
        if (w == NSEG - 1) {
            // epilogue row 1024: buf[0] was reloaded at it=12 from off4[base+16],
            // whose .x slot is off_s[1024]
            GATE4(buf[0][0], xs_s[1024], xs_s[1025]);       // xs_s[1025] = MAXT pad
        }
    }

    const float c0 = (bd0 > 0.0f) ? bn0 / bd0 : MAXT;       // exact IEEE div
    const float c1 = (bd1 > 0.0f) ? bn1 / bd1 : MAXT;
    const float c2 = (bd2 > 0.0f) ? bn2 / bd2 : MAXT;
    const float c3 = (bd3 > 0.0f) ? bn3 / bd3 : MAXT;
    *(float4*)&best[w][lane * 4] = make_float4(c0, c1, c2, c3);
    __syncthreads();

    // ---- cross-segment min + store ----
    if (tid < 256) {
        float r = best[0][tid];
#pragma unroll
        for (int s = 1; s < NSEG; ++s) r = fminf(r, best[s][tid]);
        out[b * M_OUT + blockIdx.x * 256 + tid] = r;
    }
}

extern "C" void kernel_launch(void* const* d_in, const int* in_sizes, int n_in,
                              void* d_out, int out_size, void* d_ws, size_t ws_size,
                              hipStream_t stream) {
    const float* X = (const float*)d_in[0];   // [64, 1024]
    const float* W = (const float*)d_in[1];   // [1025, 1024]
    float* out = (float*)d_out;               // [64, 1024]

    float* sx   = (float*)d_ws;                                        // [64, PITCH]
    int*   soff = (int*)((char*)d_ws + BATCH * PITCH * sizeof(float)); // [64, PITCH]

    dim3 g1(5, BATCH);
    rank_kernel<<<g1, 512, 0, stream>>>(X, sx, soff);

    dim3 g2(M_OUT / 256, BATCH);
    snn_scan<<<g2, 1024, 0, stream>>>(W, sx, soff, out);
}

// Round 17
// 110.869 us; speedup vs baseline: 2.4027x; 2.2833x over previous
//
#include <hip/hip_runtime.h>
#include <math.h>

#define MAXT 100000.0f
#define M_OUT 1024
#define BATCH 64
#define PITCH 1040      // 1025 real + pads covering depth-4 offset overrun (off4 idx <= 259)
#define NSEG 8
#define SEGLEN 128
#define CPB 128         // columns per block (2 per lane)

#define WALL() __builtin_amdgcn_sched_barrier(0)

// ---------------------------------------------------------------------------
// Kernel 1 (R13, verified): stable rank via u32 keys, split-j.
// key = ((mantissa bits) >> 2) << 11 | index — ties fall to index order =
// adjacent-swap perturbation, compensated (validated R9-R16: absmax 16).
// Writes TRUE x to sx, byte row offsets to soff; rewrites pads [1025,1040)
// every launch (ws re-poisoned 0xAA).
// ---------------------------------------------------------------------------
__global__ __launch_bounds__(512) void rank_kernel(const float* __restrict__ X,
                                                   float* __restrict__ sx,
                                                   int* __restrict__ soff) {
    const int b   = blockIdx.y;
    const int tid = threadIdx.x;            // 0..511
    const int t   = tid & 255;              // key slot within block
    const int i   = blockIdx.x * 256 + t;   // key index 0..1279
    __shared__ __align__(16) unsigned keys[1032];
    __shared__ int part[256];

    const float myx = (i < 1024) ? X[b * 1024 + i] : 1.0f;

#pragma unroll
    for (int c = 0; c < 2; ++c) {
        const int ii = c * 512 + tid;
        const float v = X[b * 1024 + ii];
        keys[ii] = (((__float_as_uint(v) - 0x3F800000u) >> 2) << 11) | (unsigned)ii;
    }
    if (tid == 0) keys[1024] = 1024u;                       // bias: mantissa 0 | idx 1024
    else if (tid < 8) keys[1024 + tid] = 0xFFFFFFFFu;       // pads: > all real keys
    __syncthreads();

    const unsigned ki = keys[(i < 1032) ? i : 1031];        // guard OOB LDS read
    const int j0 = (tid < 256) ? 0 : 516;
    int r0 = 0, r1 = 0;
#pragma unroll 8
    for (int j = j0; j < j0 + 512; j += 8) {
        const uint4 a = *(const uint4*)&keys[j];
        const uint4 c = *(const uint4*)&keys[j + 4];
        r0 += (int)(a.x < ki) + (int)(a.y < ki) + (int)(a.z < ki) + (int)(a.w < ki);
        r1 += (int)(c.x < ki) + (int)(c.y < ki) + (int)(c.z < ki) + (int)(c.w < ki);
    }
    {   // 516 = 512 + last quad of the half-range
        const uint4 a = *(const uint4*)&keys[j0 + 512];
        r0 += (int)(a.x < ki) + (int)(a.y < ki) + (int)(a.z < ki) + (int)(a.w < ki);
    }
    if (tid >= 256) part[t] = r0 + r1;
    __syncthreads();

    if (tid < 256) {
        if (i <= 1024) {
            const int rank = r0 + r1 + part[t];
            sx[b * PITCH + rank]   = myx;
            soff[b * PITCH + rank] = i * 4096;              // byte offset into W
        } else if (i < PITCH) {
            sx[b * PITCH + i] = MAXT; soff[b * PITCH + i] = 0;  // sentinels
        }
    }
}

// ---------------------------------------------------------------------------
// Kernel 2: decoupled two-pass K-scan, 512-THREAD GEOMETRY (R16 post-mortem:
// every 1024-thr kernel is capped at 64 VGPR by the allocator regardless of
// launch_bounds/waves_per_eu -> depth-4 float4 buffers spilled, twice).
// 8 waves = 8 segments x 128 rows; 2 cols/lane (float2); grid (8,64) = 512
// blocks = 2 blocks/CU = same 4 waves/SIMD TLP as R14. Depth-4 circular
// buffer is now 32 VGPRs (4 bufs x 4 rows x float2) -> fits WITHOUT spill
// even under a 64-VGPR cap, with 12 loads in flight and load->use distance
// ~3 compute sections. Step algebra unchanged since R11 (absmax 16).
// ---------------------------------------------------------------------------
__global__ __launch_bounds__(512, 2) void snn_scan(const float* __restrict__ W,
                                                   const float* __restrict__ sx,
                                                   const int* __restrict__ soff,
                                                   float* __restrict__ out) {
    const int b    = blockIdx.y;
    const int tid  = threadIdx.x;
    const int w    = tid >> 6;        // wave = K-segment id, 0..7
    const int lane = tid & 63;

    __shared__ __align__(16) float xs_s[PITCH];
    __shared__ __align__(16) int   off_s[PITCH];
    __shared__ __align__(8)  float segw [NSEG][CPB];
    __shared__ __align__(8)  float segwt[NSEG][CPB];
    __shared__ __align__(8)  float best [NSEG][CPB];

    for (int i = tid; i < PITCH; i += 512) {
        xs_s[i]  = sx[b * PITCH + i];
        off_s[i] = soff[b * PITCH + i];
    }
    __syncthreads();

    const char* Wq = (const char*)W + (size_t)(blockIdx.x * CPB + lane * 2) * 4;
    const int4* off4 = (const int4*)off_s;
    const int k0 = w * SEGLEN;
    const int base = k0 >> 2;         // first int4 slot of this segment

#define LOADB(dst, o)                                                          \
    do {                                                                       \
        dst[0] = *(const float2*)(Wq + (o).x);                                 \
        dst[1] = *(const float2*)(Wq + (o).y);                                 \
        dst[2] = *(const float2*)(Wq + (o).z);                                 \
        dst[3] = *(const float2*)(Wq + (o).w);                                 \
    } while (0)

    float cw0 = 0, cw1 = 0, ct0 = 0, ct1 = 0;

#define ACC2(wv, xx)                                                           \
    do {                                                                       \
        cw0 = __fadd_rn(cw0, (wv).x); ct0 = __builtin_fmaf((wv).x, (xx), ct0); \
        cw1 = __fadd_rn(cw1, (wv).y); ct1 = __builtin_fmaf((wv).y, (xx), ct1); \
    } while (0)

    // ---- pass 1: segment sums, depth-4 circular pipeline (32 iters) ----
    {
        float2 buf[4][4];
#pragma unroll
        for (int p = 0; p < 4; ++p) { const int4 o = off4[base + p]; LOADB(buf[p], o); }
        WALL();
#pragma unroll
        for (int it = 0; it < 32; ++it) {
            const int k = k0 + it * 4;
            ACC2(buf[it & 3][0], xs_s[k]);
            ACC2(buf[it & 3][1], xs_s[k + 1]);
            ACC2(buf[it & 3][2], xs_s[k + 2]);
            ACC2(buf[it & 3][3], xs_s[k + 3]);
            WALL();
            const int4 o = off4[base + it + 4];    // pads safe (<= off4[259])
            LOADB(buf[it & 3], o);
            WALL();
        }
    }
    *(float2*)&segw[w][lane * 2]  = make_float2(cw0, cw1);
    *(float2*)&segwt[w][lane * 2] = make_float2(ct0, ct1);
    __syncthreads();

    // ---- exclusive prefix over segments (ascending s) ----
    cw0 = cw1 = ct0 = ct1 = 0.0f;
    for (int s = 0; s < w; ++s) {
        const float2 a = *(const float2*)&segw[s][lane * 2];
        const float2 t = *(const float2*)&segwt[s][lane * 2];
        cw0 = __fadd_rn(cw0, a.x); cw1 = __fadd_rn(cw1, a.y);
        ct0 = __fadd_rn(ct0, t.x); ct1 = __fadd_rn(ct1, t.y);
    }

    // ---- pass 2: gated scan, first-valid lock, depth-4 circular pipeline ----
    float bn0 = 0, bn1 = 0;
    float bd0 = -1.0f, bd1 = -1.0f;

#define GATE(cwv, ctv, bnv, bdv, wvv, xx, xxn)                                 \
    do {                                                                       \
        cwv = __fadd_rn(cwv, (wvv));                                           \
        ctv = __builtin_fmaf((wvv), (xx), ctv);                                \
        const float dn = __fadd_rn(cwv, -1.0f);                                \
        const bool v = (ctv >= __fmul_rn((xx), dn))                            \
                     & (ctv <= __fmul_rn((xxn), dn));                          \
        const bool u = v & (bdv < 0.0f);                                       \
        bnv = u ? ctv : bnv;                                                   \
        bdv = u ? dn  : bdv;                                                   \
    } while (0)

#define GATE2(wv, xx, xxn)                                                     \
    do {                                                                       \
        GATE(cw0, ct0, bn0, bd0, (wv).x, (xx), (xxn));                         \
        GATE(cw1, ct1, bn1, bd1, (wv).y, (xx), (xxn));                         \
    } while (0)

    {
        float2 buf[4][4];
#pragma unroll
        for (int p = 0; p < 4; ++p) { const int4 o = off4[base + p]; LOADB(buf[p], o); }
        WALL();
#pragma unroll
        for (int it = 0; it < 32; ++it) {
            const int k = k0 + it * 4;
            const float xa = xs_s[k],     xb = xs_s[k + 1];
            const float xc = xs_s[k + 2], xd = xs_s[k + 3], xe = xs_s[k + 4];
            GATE2(buf[it & 3][0], xa, xb);
            GATE2(buf[it & 3][1], xb, xc);
            GATE2(buf[it & 3][2], xc, xd);
            GATE2(buf[it & 3][3], xd, xe);
            WALL();
            const int4 o = off4[base + it + 4];
            LOADB(buf[it & 3], o);
            WALL();
        }
        if (w == NSEG - 1) {
            // epilogue row 1024: at it=28 buf[0] was reloaded from off4[256],
            // whose .x slot is off_s[1024]
            GATE2(buf[0][0], xs_s[1024], xs_s[1025]);       // xs_s[1025] = MAXT pad
        }
    }

    const float c0 = (bd0 > 0.0f) ? bn0 / bd0 : MAXT;       // exact IEEE div
    const float c1 = (bd1 > 0.0f) ? bn1 / bd1 : MAXT;
    *(float2*)&best[w][lane * 2] = make_float2(c0, c1);
    __syncthreads();

    // ---- cross-segment min + store ----
    if (tid < CPB) {
        float r = best[0][tid];
#pragma unroll
        for (int s = 1; s < NSEG; ++s) r = fminf(r, best[s][tid]);
        out[b * M_OUT + blockIdx.x * CPB + tid] = r;
    }
}

extern "C" void kernel_launch(void* const* d_in, const int* in_sizes, int n_in,
                              void* d_out, int out_size, void* d_ws, size_t ws_size,
                              hipStream_t stream) {
    const float* X = (const float*)d_in[0];   // [64, 1024]
    const float* W = (const float*)d_in[1];   // [1025, 1024]
    float* out = (float*)d_out;               // [64, 1024]

    float* sx   = (float*)d_ws;                                        // [64, PITCH]
    int*   soff = (int*)((char*)d_ws + BATCH * PITCH * sizeof(float)); // [64, PITCH]

    dim3 g1(5, BATCH);
    rank_kernel<<<g1, 512, 0, stream>>>(X, sx, soff);

    dim3 g2(M_OUT / CPB, BATCH);
    snn_scan<<<g2, 512, 0, stream>>>(W, sx, soff, out);
}